// Round 10
// baseline (225.991 us; speedup 1.0000x reference)
//
#include <hip/hip_runtime.h>
#include <math.h>

// ConvolutionalCapsule with EM routing, fully fused. Round-10 decomposition:
// grid 288, block 1024, ONE position per block, IPT=9 (32 half-waves x 9 i).
// Rationale (R6-R9 TLP sweep): R7 (2 waves/SIMD) 129us -> R9 (4 waves/SIMD,
// full co-residency, no tail) 119us => TLP nearly useless, VALUBusy 18.6%
// => bound by each wave's own serial per-iteration critical path (~5.3K
// cy/iter x 54 iters). Only never-varied knob: iterations/wave. This config
// halves it (54 -> 27). R1 ran this shape at 280us but with a ~40-reg spill
// cascade (old 100-reg body); today's body is ~8 over the immovable 64 cap
// (R9: WRITE 2.3MB, mild). Co-residency: 288 blocks x 16 waves = 4608 waves;
// 32 CUs host 2 blocks (LDS 62KB<160, VGPR 64 => 8 w/SIMD) => no tail round.
// Key algebraic facts (proven R3-R9):
//  - var = UNWEIGHTED sum_i (v-M)^2 => S1,S2 iteration-invariant.
//  - Kmax = max_c Kc shift => exp2 args <= 0, denom >= e^-8, no per-i max.
//  - cost = rsum * (16*beta_v + sum_d log(stdv+eps)).
//  - DPP row reduce (R7); parallel statsA/statsB (R6); I2L pre-scaled (R8).
// Thread map: c = t&31, isub = t>>5 (0..31), i = isub*9 + j.

#define EPSF 1e-7f
#define KKI 288
#define NC 32
#define NTHREADS 1024
#define IPT 9           // KKI / 32 half-waves
#define ST 17           // padded stride: (17c+d)%32 bijective over c
#define L2E 1.4426950408889634f

__device__ __forceinline__ float rcp_fast(float v) { return __builtin_amdgcn_rcpf(v); }

// DPP-based cross-lane (VALU pipe; proven R7)
template <int CTRL>
__device__ __forceinline__ float dpp_mov_f(float x) {
    return __int_as_float(__builtin_amdgcn_update_dpp(
        0, __float_as_int(x), CTRL, 0xF, 0xF, true));
}
__device__ __forceinline__ float row_sum16(float x) {
    x += dpp_mov_f<0xB1>(x);    // quad_perm xor1
    x += dpp_mov_f<0x4E>(x);    // quad_perm xor2
    x += dpp_mov_f<0x124>(x);   // row_ror:4
    x += dpp_mov_f<0x128>(x);   // row_ror:8
    return x;
}
__device__ __forceinline__ float row_max16(float x) {
    x = fmaxf(x, dpp_mov_f<0xB1>(x));
    x = fmaxf(x, dpp_mov_f<0x4E>(x));
    x = fmaxf(x, dpp_mov_f<0x124>(x));
    x = fmaxf(x, dpp_mov_f<0x128>(x));
    return x;
}

__global__ __launch_bounds__(NTHREADS)
void caps_em_kernel(const float* __restrict__ x, const float* __restrict__ Wg,
                    const float* __restrict__ beta_v, const float* __restrict__ beta_a,
                    float* __restrict__ out)
{
    __shared__ float MpL[KKI * 16];   // patch poses
    __shared__ float apL[KKI];        // patch activations
    __shared__ float T1L[NC * ST];    // sum_i Rw*v      (per iteration)
    __shared__ float S1L[NC * ST];    // sum_i v         (iteration-invariant)
    __shared__ float S2L[NC * ST];    // sum_i v^2       (iteration-invariant)
    __shared__ float ML[NC * ST];     // M
    __shared__ float I2L[NC * ST];    // 0.5/var * log2e (pre-scaled)
    __shared__ float RsumL[NC];
    __shared__ float constL[NC];      // Kc = log(a_j+eps) - sum_d log(stdv+eps)
    __shared__ float slogL[NC];
    __shared__ float costL[NC];
    __shared__ float aoutL[NC];       // sigmoid(a_j)
    __shared__ float KmaxL;           // max_c Kc

    const int t = threadIdx.x;
    const int bid = blockIdx.x;           // b*144 + ho*12 + wo
    const int b = bid / 144;
    const int rem = bid - b * 144;
    const int ho = rem / 12;
    const int wo = rem - ho * 12;

    const int c = t & 31;
    const int isub = t >> 5;              // 0..31
    const int iBase = isub * IPT;

    // ---- stage patch tile: Mp[i][0..15], ap[i], i = p*32+cin, p = di*3+dj ----
    for (int idx = t; idx < KKI * 17; idx += NTHREADS) {
        int i = idx / 17;
        int e = idx - i * 17;
        int p = i >> 5, cin = i & 31;
        int di = p / 3, dj = p - di * 3;
        float vx = x[(((b * 14 + (ho + di)) * 14 + (wo + dj)) * 32 + cin) * 17 + e];
        if (e < 16) MpL[i * 16 + e] = vx; else apL[i] = vx;
    }
    if (t < NC * ST) { T1L[t] = 0.f; S1L[t] = 0.f; S2L[t] = 0.f; }
    if (t < NC) RsumL[t] = 0.f;
    __syncthreads();

    // stats A: 512 threads, one per (cc = t>>4, d = t&15);
    // d = lane bits 0-3 => pure-DPP row sum for slog.
    auto statsA = [&]() {
        if (t < 512) {
            const int cc = t >> 4, d = t & 15;
            float rsum = RsumL[cc];
            float m = T1L[cc * ST + d] * rcp_fast(rsum);
            float var = S2L[cc * ST + d] - 2.f * m * S1L[cc * ST + d] + 288.f * m * m;
            var = fmaxf(var, 0.f);
            float lg = logf(sqrtf(var) + EPSF);
            ML[cc * ST + d] = m;
            I2L[cc * ST + d] = 0.5f * L2E * rcp_fast(var);
            float sl = row_sum16(lg);
            if (d == 0) {
                slogL[cc] = sl;
                costL[cc] = rsum * (16.f * beta_v[cc] + sl);
            }
        }
    };
    // stats B: cross-capsule mean/std + activation + Kmax (32 threads).
    auto statsB = [&](float inv_temp) {
        if (t < 32) {
            float cost = costL[t];
            float csum = row_sum16(cost); csum += __shfl_xor(csum, 16);
            float c_mean = csum * 0.03125f;
            float diff = cost - c_mean;
            float dsq = row_sum16(diff * diff); dsq += __shfl_xor(dsq, 16);
            float c_stdv = sqrtf(dsq * 0.03125f);
            float a_cost = beta_a[t] + (c_mean - cost) * rcp_fast(c_stdv + EPSF);
            float a_j = 1.f / (1.f + expf(-inv_temp * a_cost));
            float kc = logf(a_j + EPSF) - slogL[t];
            constL[t] = kc;
            aoutL[t] = 1.f / (1.f + expf(-a_j));
            float km = row_max16(kc); km = fmaxf(km, __shfl_xor(km, 16));
            if (t == 0) KmaxL = km;
        }
    };

    // ---- pass 0: R uniform 1/32 -> Rw = ap/32; also build S1,S2 ----
    {
        float t1[16], s1[16], s2[16];
        #pragma unroll
        for (int d = 0; d < 16; ++d) { t1[d] = 0.f; s1[d] = 0.f; s2[d] = 0.f; }
        float rsum = 0.f;
        for (int j = 0; j < IPT; ++j) {
            const int i = iBase + j;
            float wa[16], ma[16];
            const float4* w4 = (const float4*)(Wg + ((size_t)((i << 5) + c) << 4));
            ((float4*)wa)[0] = w4[0]; ((float4*)wa)[1] = w4[1];
            ((float4*)wa)[2] = w4[2]; ((float4*)wa)[3] = w4[3];
            const float4* mp4 = (const float4*)(MpL + (i << 4));
            ((float4*)ma)[0] = mp4[0]; ((float4*)ma)[1] = mp4[1];
            ((float4*)ma)[2] = mp4[2]; ((float4*)ma)[3] = mp4[3];
            float rw = apL[i] * 0.03125f;
            rsum += rw;
            #pragma unroll
            for (int p = 0; p < 4; ++p)
                #pragma unroll
                for (int r = 0; r < 4; ++r) {
                    float acc = ma[p * 4 + 0] * wa[0 * 4 + r];
                    acc = fmaf(ma[p * 4 + 1], wa[1 * 4 + r], acc);
                    acc = fmaf(ma[p * 4 + 2], wa[2 * 4 + r], acc);
                    acc = fmaf(ma[p * 4 + 3], wa[3 * 4 + r], acc);
                    const int d = p * 4 + r;
                    t1[d] = fmaf(rw, acc, t1[d]);
                    s1[d] += acc;
                    s2[d] = fmaf(acc, acc, s2[d]);
                }
        }
        // combine partner half-waves (lane^32 shares c), then 32 lanes atomic
        rsum += __shfl_xor(rsum, 32);
        #pragma unroll
        for (int d = 0; d < 16; ++d) {
            t1[d] += __shfl_xor(t1[d], 32);
            s1[d] += __shfl_xor(s1[d], 32);
            s2[d] += __shfl_xor(s2[d], 32);
        }
        if ((t & 32) == 0) {
            atomicAdd(&RsumL[c], rsum);
            #pragma unroll
            for (int d = 0; d < 16; ++d) {
                atomicAdd(&T1L[c * ST + d], t1[d]);
                atomicAdd(&S1L[c * ST + d], s1[d]);
                atomicAdd(&S2L[c * ST + d], s2[d]);
            }
        }
        __syncthreads();
        statsA();
        __syncthreads();
        statsB(1.0f);   // it = 0
        __syncthreads();
    }

    // ---- passes 1,2: fused E-step (softmax over c, in-register) + M-step ----
    for (int it = 1; it < 3; ++it) {
        float Mreg[16], i2[16];
        #pragma unroll
        for (int d = 0; d < 16; ++d) {
            Mreg[d] = ML[c * ST + d];
            i2[d]   = I2L[c * ST + d];         // already log2-space scaled
        }
        float Kc2 = (constL[c] - KmaxL) * L2E; // exp2 arg <= 0 always
        __syncthreads();                       // all reads done before re-zero
        if (t < NC * ST) T1L[t] = 0.f;
        if (t < NC) RsumL[t] = 0.f;
        __syncthreads();

        float t1[16];
        #pragma unroll
        for (int d = 0; d < 16; ++d) t1[d] = 0.f;
        float rsum = 0.f;
        for (int j = 0; j < IPT; ++j) {
            const int i = iBase + j;
            float wa[16], ma[16];
            const float4* w4 = (const float4*)(Wg + ((size_t)((i << 5) + c) << 4));
            ((float4*)wa)[0] = w4[0]; ((float4*)wa)[1] = w4[1];
            ((float4*)wa)[2] = w4[2]; ((float4*)wa)[3] = w4[3];
            const float4* mp4 = (const float4*)(MpL + (i << 4));
            ((float4*)ma)[0] = mp4[0]; ((float4*)ma)[1] = mp4[1];
            ((float4*)ma)[2] = mp4[2]; ((float4*)ma)[3] = mp4[3];
            float a_i = apL[i];
            float v[16];
            #pragma unroll
            for (int p = 0; p < 4; ++p)
                #pragma unroll
                for (int r = 0; r < 4; ++r) {
                    float acc = ma[p * 4 + 0] * wa[0 * 4 + r];
                    acc = fmaf(ma[p * 4 + 1], wa[1 * 4 + r], acc);
                    acc = fmaf(ma[p * 4 + 2], wa[2 * 4 + r], acc);
                    acc = fmaf(ma[p * 4 + 3], wa[3 * 4 + r], acc);
                    v[p * 4 + r] = acc;
                }
            // two 8-deep partial chains (R8, passed)
            float lpa = 0.f, lpb = 0.f;
            #pragma unroll
            for (int d = 0; d < 8; ++d) {
                float df = v[d] - Mreg[d];
                lpa = fmaf(-df * df, i2[d], lpa);
            }
            #pragma unroll
            for (int d = 8; d < 16; ++d) {
                float df = v[d] - Mreg[d];
                lpb = fmaf(-df * df, i2[d], lpb);
            }
            float ex = exp2f(Kc2 + lpa + lpb); // <= 1; denom >= e^-8: safe
            // softmax denominator over the 32 caps of this half-wave:
            // DPP row sum (lane bits 0-3) + one cross-row shfl (bit 4)
            float ssum = row_sum16(ex);
            ssum += __shfl_xor(ssum, 16);
            float rw = ex * rcp_fast(ssum) * a_i;
            rsum += rw;
            #pragma unroll
            for (int d = 0; d < 16; ++d) t1[d] = fmaf(rw, v[d], t1[d]);
        }
        rsum += __shfl_xor(rsum, 32);
        #pragma unroll
        for (int d = 0; d < 16; ++d) t1[d] += __shfl_xor(t1[d], 32);
        if ((t & 32) == 0) {
            atomicAdd(&RsumL[c], rsum);
            #pragma unroll
            for (int d = 0; d < 16; ++d) atomicAdd(&T1L[c * ST + d], t1[d]);
        }
        __syncthreads();
        statsA();
        __syncthreads();
        statsB(1.0f + (float)it);   // inv_temp = 1 + it
        __syncthreads();
    }

    // ---- epilogue: out[b,ho,wo,c,0:16]=M, out[...,16]=sigmoid(a_j) ----
    // output stride per capsule is 17 == ST, so ML indexes line up directly.
    if (t < NC * 17) {
        int cc = t / 17;
        int e = t - cc * 17;
        float val = (e < 16) ? ML[t] : aoutL[cc];
        out[(size_t)bid * (NC * 17) + t] = val;
    }
}

extern "C" void kernel_launch(void* const* d_in, const int* in_sizes, int n_in,
                              void* d_out, int out_size, void* d_ws, size_t ws_size,
                              hipStream_t stream) {
    const float* x  = (const float*)d_in[0];
    const float* W  = (const float*)d_in[1];
    const float* bv = (const float*)d_in[2];
    const float* ba = (const float*)d_in[3];
    float* out = (float*)d_out;
    // grid = B*Ho*Wo = 2*12*12 = 288 positions, one block each
    caps_em_kernel<<<288, NTHREADS, 0, stream>>>(x, W, bv, ba, out);
}

// Round 11
// 188.656 us; speedup vs baseline: 1.1979x; 1.1979x over previous
//
#include <hip/hip_runtime.h>
#include <math.h>

// ConvolutionalCapsule with EM routing, fully fused. Round-11 = R9 structure
// (grid 144, block 1024 = two independent 512-thread units, one position
// each; no dispatch tail) with ONE mechanism change:
//   ma/ap are loaded DIRECTLY FROM GLOBAL x each iteration (L1/L2-resident
//   broadcast: all 32 lanes of a half-wave read the same contiguous 68B).
//   LDS staging (MpL/apL) deleted.
// Rationale (R6-R10 accounting): R9 wall = 285K cy vs ~50K cy VALU issue;
// 4-deep TLP doesn't fill it; the only resource serializing ALL waves on a
// CU is the single per-CU LDS pipe (6 LDS ops/iter/wave x 16 waves x 54
// iters ~ 5.2K wave-ops ~ 100-200K cy occupancy). Retro-explains R6's -48us
// (biggest LDS-op removal) and R7's -8us (DPP). This round moves 5 of 6
// per-iter LDS ops to the idle vector-memory pipe (HBM 0.8%, x rows are
// 64B-contiguous + a_i on the same line, dword-aligned dwordx4 is legal).
// Softmax shfl_xor(16) kept (proven primitive; permlane swap is the next
// isolated delta if this confirms).
// Proven set carried: Kmax shift, parallel statsA/B, DPP row reduce,
// I2L pre-scaled by log2e, ST=17 bijective LDS-atomic banks.
// R10 lesson: IPT=9 @1024thr spills in-loop (WRITE 11MB) and regresses.
// Unit thread map: c = u&31, isub = u>>5 (0..15), i = isub*18 + j.

#define EPSF 1e-7f
#define KKI 288
#define NC 32
#define NTHREADS 1024
#define UNIT 512
#define IPT 18          // KKI / 16 half-waves per unit
#define ST 17           // padded stride: (17c+d)%32 bijective over c
#define L2E 1.4426950408889634f

__device__ __forceinline__ float rcp_fast(float v) { return __builtin_amdgcn_rcpf(v); }

// DPP-based cross-lane (VALU pipe; proven R7)
template <int CTRL>
__device__ __forceinline__ float dpp_mov_f(float x) {
    return __int_as_float(__builtin_amdgcn_update_dpp(
        0, __float_as_int(x), CTRL, 0xF, 0xF, true));
}
__device__ __forceinline__ float row_sum16(float x) {
    x += dpp_mov_f<0xB1>(x);    // quad_perm xor1
    x += dpp_mov_f<0x4E>(x);    // quad_perm xor2
    x += dpp_mov_f<0x124>(x);   // row_ror:4
    x += dpp_mov_f<0x128>(x);   // row_ror:8
    return x;
}
__device__ __forceinline__ float row_max16(float x) {
    x = fmaxf(x, dpp_mov_f<0xB1>(x));
    x = fmaxf(x, dpp_mov_f<0x4E>(x));
    x = fmaxf(x, dpp_mov_f<0x124>(x));
    x = fmaxf(x, dpp_mov_f<0x128>(x));
    return x;
}

__global__ __launch_bounds__(NTHREADS)
void caps_em_kernel(const float* __restrict__ x, const float* __restrict__ Wg,
                    const float* __restrict__ beta_v, const float* __restrict__ beta_a,
                    float* __restrict__ out)
{
    // per-unit LDS (H = 0/1). ~11KB each, ~22KB total (staging removed).
    __shared__ float T1L[2][NC * ST];
    __shared__ float S1L[2][NC * ST];
    __shared__ float S2L[2][NC * ST];
    __shared__ float ML[2][NC * ST];
    __shared__ float I2L[2][NC * ST];   // 0.5/var * log2e (pre-scaled)
    __shared__ float RsumL[2][NC];
    __shared__ float constL[2][NC];
    __shared__ float slogL[2][NC];
    __shared__ float costL[2][NC];
    __shared__ float aoutL[2][NC];
    __shared__ float KmaxL[2];

    const int t = threadIdx.x;
    const int H = t >> 9;                 // unit id (waves never straddle)
    const int u = t & 511;                // unit-local thread id
    const int pos = blockIdx.x * 2 + H;   // 0..287 = b*144 + ho*12 + wo
    const int b = pos / 144;
    const int rem = pos - b * 144;
    const int ho = rem / 12;
    const int wo = rem - ho * 12;

    const int c = u & 31;
    const int isub = u >> 5;              // 0..15
    const int iBase = isub * IPT;

    for (int idx = u; idx < NC * ST; idx += UNIT) { T1L[H][idx] = 0.f; S1L[H][idx] = 0.f; S2L[H][idx] = 0.f; }
    if (u < NC) RsumL[H][u] = 0.f;
    __syncthreads();

    // x row for input capsule i: 16 pose floats (contiguous) + a at [16].
    auto xrow = [&](int i) -> const float* {
        const int p = i >> 5, cin = i & 31;
        const int di = (p * 11) >> 5;     // p/3 for p in [0,8]
        const int dj = p - di * 3;
        return x + ((size_t)((b * 14 + ho + di) * 14 + (wo + dj)) * 32 + cin) * 17;
    };

    // stats A: 512 unit-threads, one per (cc = u>>4, d = u&15);
    // d = lane bits 0-3 => pure-DPP row sum for slog.
    auto statsA = [&]() {
        const int cc = u >> 4, d = u & 15;
        float rsum = RsumL[H][cc];
        float m = T1L[H][cc * ST + d] * rcp_fast(rsum);
        float var = S2L[H][cc * ST + d] - 2.f * m * S1L[H][cc * ST + d] + 288.f * m * m;
        var = fmaxf(var, 0.f);
        float lg = logf(sqrtf(var) + EPSF);
        ML[H][cc * ST + d] = m;
        I2L[H][cc * ST + d] = 0.5f * L2E * rcp_fast(var);
        float sl = row_sum16(lg);
        if (d == 0) {
            slogL[H][cc] = sl;
            costL[H][cc] = rsum * (16.f * beta_v[cc] + sl);
        }
    };
    // stats B: cross-capsule mean/std + activation + Kmax (32 unit-threads).
    auto statsB = [&](float inv_temp) {
        if (u < 32) {
            float cost = costL[H][u];
            float csum = row_sum16(cost); csum += __shfl_xor(csum, 16);
            float c_mean = csum * 0.03125f;
            float diff = cost - c_mean;
            float dsq = row_sum16(diff * diff); dsq += __shfl_xor(dsq, 16);
            float c_stdv = sqrtf(dsq * 0.03125f);
            float a_cost = beta_a[u] + (c_mean - cost) * rcp_fast(c_stdv + EPSF);
            float a_j = 1.f / (1.f + expf(-inv_temp * a_cost));
            float kc = logf(a_j + EPSF) - slogL[H][u];
            constL[H][u] = kc;
            aoutL[H][u] = 1.f / (1.f + expf(-a_j));
            float km = row_max16(kc); km = fmaxf(km, __shfl_xor(km, 16));
            if (u == 0) KmaxL[H] = km;
        }
    };

    // ---- pass 0: R uniform 1/32 -> Rw = ap/32; also build S1,S2 ----
    {
        float t1[16], s1[16], s2[16];
        #pragma unroll
        for (int d = 0; d < 16; ++d) { t1[d] = 0.f; s1[d] = 0.f; s2[d] = 0.f; }
        float rsum = 0.f;
        for (int j = 0; j < IPT; ++j) {
            const int i = iBase + j;
            const float* xr = xrow(i);
            float wa[16], ma[16];
            const float4* w4 = (const float4*)(Wg + ((size_t)((i << 5) + c) << 4));
            ((float4*)wa)[0] = w4[0]; ((float4*)wa)[1] = w4[1];
            ((float4*)wa)[2] = w4[2]; ((float4*)wa)[3] = w4[3];
            ((float4*)ma)[0] = ((const float4*)xr)[0];
            ((float4*)ma)[1] = ((const float4*)xr)[1];
            ((float4*)ma)[2] = ((const float4*)xr)[2];
            ((float4*)ma)[3] = ((const float4*)xr)[3];
            float rw = xr[16] * 0.03125f;
            rsum += rw;
            #pragma unroll
            for (int p = 0; p < 4; ++p)
                #pragma unroll
                for (int r = 0; r < 4; ++r) {
                    float acc = ma[p * 4 + 0] * wa[0 * 4 + r];
                    acc = fmaf(ma[p * 4 + 1], wa[1 * 4 + r], acc);
                    acc = fmaf(ma[p * 4 + 2], wa[2 * 4 + r], acc);
                    acc = fmaf(ma[p * 4 + 3], wa[3 * 4 + r], acc);
                    const int d = p * 4 + r;
                    t1[d] = fmaf(rw, acc, t1[d]);
                    s1[d] += acc;
                    s2[d] = fmaf(acc, acc, s2[d]);
                }
        }
        // combine partner half-waves (lane^32 shares c), then 32 lanes atomic
        rsum += __shfl_xor(rsum, 32);
        #pragma unroll
        for (int d = 0; d < 16; ++d) {
            t1[d] += __shfl_xor(t1[d], 32);
            s1[d] += __shfl_xor(s1[d], 32);
            s2[d] += __shfl_xor(s2[d], 32);
        }
        if ((u & 32) == 0) {
            atomicAdd(&RsumL[H][c], rsum);
            #pragma unroll
            for (int d = 0; d < 16; ++d) {
                atomicAdd(&T1L[H][c * ST + d], t1[d]);
                atomicAdd(&S1L[H][c * ST + d], s1[d]);
                atomicAdd(&S2L[H][c * ST + d], s2[d]);
            }
        }
        __syncthreads();
        statsA();
        __syncthreads();
        statsB(1.0f);   // it = 0
        __syncthreads();
    }

    // ---- passes 1,2: fused E-step (softmax over c, in-register) + M-step ----
    for (int it = 1; it < 3; ++it) {
        float Mreg[16], i2[16];
        #pragma unroll
        for (int d = 0; d < 16; ++d) {
            Mreg[d] = ML[H][c * ST + d];
            i2[d]   = I2L[H][c * ST + d];      // already log2-space scaled
        }
        float Kc2 = (constL[H][c] - KmaxL[H]) * L2E;  // exp2 arg <= 0 always
        __syncthreads();                       // all reads done before re-zero
        for (int idx = u; idx < NC * ST; idx += UNIT) T1L[H][idx] = 0.f;
        if (u < NC) RsumL[H][u] = 0.f;
        __syncthreads();

        float t1[16];
        #pragma unroll
        for (int d = 0; d < 16; ++d) t1[d] = 0.f;
        float rsum = 0.f;
        for (int j = 0; j < IPT; ++j) {
            const int i = iBase + j;
            const float* xr = xrow(i);
            float wa[16], ma[16];
            const float4* w4 = (const float4*)(Wg + ((size_t)((i << 5) + c) << 4));
            ((float4*)wa)[0] = w4[0]; ((float4*)wa)[1] = w4[1];
            ((float4*)wa)[2] = w4[2]; ((float4*)wa)[3] = w4[3];
            ((float4*)ma)[0] = ((const float4*)xr)[0];
            ((float4*)ma)[1] = ((const float4*)xr)[1];
            ((float4*)ma)[2] = ((const float4*)xr)[2];
            ((float4*)ma)[3] = ((const float4*)xr)[3];
            float a_i = xr[16];
            float v[16];
            #pragma unroll
            for (int p = 0; p < 4; ++p)
                #pragma unroll
                for (int r = 0; r < 4; ++r) {
                    float acc = ma[p * 4 + 0] * wa[0 * 4 + r];
                    acc = fmaf(ma[p * 4 + 1], wa[1 * 4 + r], acc);
                    acc = fmaf(ma[p * 4 + 2], wa[2 * 4 + r], acc);
                    acc = fmaf(ma[p * 4 + 3], wa[3 * 4 + r], acc);
                    v[p * 4 + r] = acc;
                }
            // two 8-deep partial chains (R8, passed)
            float lpa = 0.f, lpb = 0.f;
            #pragma unroll
            for (int d = 0; d < 8; ++d) {
                float df = v[d] - Mreg[d];
                lpa = fmaf(-df * df, i2[d], lpa);
            }
            #pragma unroll
            for (int d = 8; d < 16; ++d) {
                float df = v[d] - Mreg[d];
                lpb = fmaf(-df * df, i2[d], lpb);
            }
            float ex = exp2f(Kc2 + lpa + lpb); // <= 1; denom >= e^-8: safe
            // softmax denominator over the 32 caps of this half-wave:
            // DPP row sum (lane bits 0-3) + one cross-row shfl (bit 4)
            float ssum = row_sum16(ex);
            ssum += __shfl_xor(ssum, 16);
            float rw = ex * rcp_fast(ssum) * a_i;
            rsum += rw;
            #pragma unroll
            for (int d = 0; d < 16; ++d) t1[d] = fmaf(rw, v[d], t1[d]);
        }
        rsum += __shfl_xor(rsum, 32);
        #pragma unroll
        for (int d = 0; d < 16; ++d) t1[d] += __shfl_xor(t1[d], 32);
        if ((u & 32) == 0) {
            atomicAdd(&RsumL[H][c], rsum);
            #pragma unroll
            for (int d = 0; d < 16; ++d) atomicAdd(&T1L[H][c * ST + d], t1[d]);
        }
        __syncthreads();
        statsA();
        __syncthreads();
        statsB(1.0f + (float)it);   // inv_temp = 1 + it
        __syncthreads();
    }

    // ---- epilogue: out[pos,c,0:16]=M, out[pos,c,16]=sigmoid(a_j) ----
    // output stride per capsule is 17 == ST, so ML indexes line up directly.
    for (int idx = u; idx < NC * 17; idx += UNIT) {
        int cc = idx / 17;
        int e = idx - cc * 17;
        float val = (e < 16) ? ML[H][idx] : aoutL[H][cc];
        out[(size_t)pos * (NC * 17) + idx] = val;
    }
}

extern "C" void kernel_launch(void* const* d_in, const int* in_sizes, int n_in,
                              void* d_out, int out_size, void* d_ws, size_t ws_size,
                              hipStream_t stream) {
    const float* x  = (const float*)d_in[0];
    const float* W  = (const float*)d_in[1];
    const float* bv = (const float*)d_in[2];
    const float* ba = (const float*)d_in[3];
    float* out = (float*)d_out;
    // 288 positions, 2 per block => grid 144 <= 256 CUs: single dispatch round
    caps_em_kernel<<<144, NTHREADS, 0, stream>>>(x, W, bv, ba, out);
}

// Round 12
// 169.739 us; speedup vs baseline: 1.3314x; 1.1114x over previous
//
#include <hip/hip_runtime.h>
#include <math.h>

// ConvolutionalCapsule with EM routing, fully fused. Round-12 = R9 structure
// restored (grid 144, block 1024 = two independent 512-thread units, one
// position each, LDS-staged patch tile — R11 proved global-direct is worse)
// with ONE mechanism change: the FMA-heavy inner math is PACKED FP32
// (f32x2 + __builtin_elementwise_fma -> v_pk_fma_f32), halving the
// instruction count of v-compute/lp/t1/s1/s2.
// Rationale (R6-R11 accounting): per-CU single-unit wall = 2870 cy/iter vs
// ~2000-2400 cy of aggregate 8-wave issue => CU ISSUE-BOUND (per-SIMD
// VALUBusy 17% is VALU-only and per-SIMD; sharing 2 units costs 1.84x =>
// a per-CU issue resource is ~saturated by one unit). Every null fits:
// TLP (R9/R10), W-prefetch (R8), LDS->global (R11, added instrs+latency);
// every win was an instruction-count cut (R6/R7). gfx950's 157.3TF fp32
// peak = 2x packed => v_pk_fma_f32 exists; packing cuts ~31% of the
// per-iteration stream with bit-identical fp32 arithmetic.
// Proven set carried: Kmax shift, parallel statsA/B, DPP row reduce,
// I2L pre-scaled by log2e (now also pre-negated), ST=17 bijective banks.
// Unit thread map: c = u&31, isub = u>>5 (0..15), i = isub*18 + j.

#define EPSF 1e-7f
#define KKI 288
#define NC 32
#define NTHREADS 1024
#define UNIT 512
#define IPT 18          // KKI / 16 half-waves per unit
#define ST 17           // padded stride: (17c+d)%32 bijective over c
#define L2E 1.4426950408889634f

typedef float f32x2 __attribute__((ext_vector_type(2)));

__device__ __forceinline__ float rcp_fast(float v) { return __builtin_amdgcn_rcpf(v); }
__device__ __forceinline__ f32x2 pk_fma(f32x2 a, f32x2 b, f32x2 c) {
    return __builtin_elementwise_fma(a, b, c);   // -> v_pk_fma_f32
}

// DPP-based cross-lane (VALU pipe; proven R7)
template <int CTRL>
__device__ __forceinline__ float dpp_mov_f(float x) {
    return __int_as_float(__builtin_amdgcn_update_dpp(
        0, __float_as_int(x), CTRL, 0xF, 0xF, true));
}
__device__ __forceinline__ float row_sum16(float x) {
    x += dpp_mov_f<0xB1>(x);    // quad_perm xor1
    x += dpp_mov_f<0x4E>(x);    // quad_perm xor2
    x += dpp_mov_f<0x124>(x);   // row_ror:4
    x += dpp_mov_f<0x128>(x);   // row_ror:8
    return x;
}
__device__ __forceinline__ float row_max16(float x) {
    x = fmaxf(x, dpp_mov_f<0xB1>(x));
    x = fmaxf(x, dpp_mov_f<0x4E>(x));
    x = fmaxf(x, dpp_mov_f<0x124>(x));
    x = fmaxf(x, dpp_mov_f<0x128>(x));
    return x;
}

__global__ __launch_bounds__(NTHREADS)
void caps_em_kernel(const float* __restrict__ x, const float* __restrict__ Wg,
                    const float* __restrict__ beta_v, const float* __restrict__ beta_a,
                    float* __restrict__ out)
{
    // per-unit LDS (H = 0/1). ~31KB each.
    __shared__ float MpL[2][KKI * 16];
    __shared__ float apL[2][KKI];
    __shared__ float T1L[2][NC * ST];
    __shared__ float S1L[2][NC * ST];
    __shared__ float S2L[2][NC * ST];
    __shared__ float ML[2][NC * ST];
    __shared__ float I2L[2][NC * ST];   // 0.5/var * log2e (pre-scaled)
    __shared__ float RsumL[2][NC];
    __shared__ float constL[2][NC];
    __shared__ float slogL[2][NC];
    __shared__ float costL[2][NC];
    __shared__ float aoutL[2][NC];
    __shared__ float KmaxL[2];

    const int t = threadIdx.x;
    const int H = t >> 9;                 // unit id (waves never straddle)
    const int u = t & 511;                // unit-local thread id
    const int pos = blockIdx.x * 2 + H;   // 0..287 = b*144 + ho*12 + wo
    const int b = pos / 144;
    const int rem = pos - b * 144;
    const int ho = rem / 12;
    const int wo = rem - ho * 12;

    const int c = u & 31;
    const int isub = u >> 5;              // 0..15
    const int iBase = isub * IPT;

    // ---- stage patch tile for this unit's position ----
    for (int idx = u; idx < KKI * 17; idx += UNIT) {
        int i = idx / 17;
        int e = idx - i * 17;
        int p = i >> 5, cin = i & 31;
        int di = p / 3, dj = p - di * 3;
        float vx = x[(((b * 14 + (ho + di)) * 14 + (wo + dj)) * 32 + cin) * 17 + e];
        if (e < 16) MpL[H][i * 16 + e] = vx; else apL[H][i] = vx;
    }
    for (int idx = u; idx < NC * ST; idx += UNIT) { T1L[H][idx] = 0.f; S1L[H][idx] = 0.f; S2L[H][idx] = 0.f; }
    if (u < NC) RsumL[H][u] = 0.f;
    __syncthreads();

    // stats A: 512 unit-threads, one per (cc = u>>4, d = u&15);
    // d = lane bits 0-3 => pure-DPP row sum for slog.
    auto statsA = [&]() {
        const int cc = u >> 4, d = u & 15;
        float rsum = RsumL[H][cc];
        float m = T1L[H][cc * ST + d] * rcp_fast(rsum);
        float var = S2L[H][cc * ST + d] - 2.f * m * S1L[H][cc * ST + d] + 288.f * m * m;
        var = fmaxf(var, 0.f);
        float lg = logf(sqrtf(var) + EPSF);
        ML[H][cc * ST + d] = m;
        I2L[H][cc * ST + d] = 0.5f * L2E * rcp_fast(var);
        float sl = row_sum16(lg);
        if (d == 0) {
            slogL[H][cc] = sl;
            costL[H][cc] = rsum * (16.f * beta_v[cc] + sl);
        }
    };
    // stats B: cross-capsule mean/std + activation + Kmax (32 unit-threads).
    auto statsB = [&](float inv_temp) {
        if (u < 32) {
            float cost = costL[H][u];
            float csum = row_sum16(cost); csum += __shfl_xor(csum, 16);
            float c_mean = csum * 0.03125f;
            float diff = cost - c_mean;
            float dsq = row_sum16(diff * diff); dsq += __shfl_xor(dsq, 16);
            float c_stdv = sqrtf(dsq * 0.03125f);
            float a_cost = beta_a[u] + (c_mean - cost) * rcp_fast(c_stdv + EPSF);
            float a_j = 1.f / (1.f + expf(-inv_temp * a_cost));
            float kc = logf(a_j + EPSF) - slogL[H][u];
            constL[H][u] = kc;
            aoutL[H][u] = 1.f / (1.f + expf(-a_j));
            float km = row_max16(kc); km = fmaxf(km, __shfl_xor(km, 16));
            if (u == 0) KmaxL[H] = km;
        }
    };

    // packed vote compute: vv[p*2+rr] = (v[p*4+2rr], v[p*4+2rr+1])
    auto computeV = [&](const float (&wa)[16], const float (&ma)[16], f32x2 (&vv)[8]) {
        const f32x2* w2 = (const f32x2*)wa;   // w2[q*2+rr]
        #pragma unroll
        for (int p = 0; p < 4; ++p) {
            f32x2 m0 = ma[p * 4 + 0], m1 = ma[p * 4 + 1];
            f32x2 m2 = ma[p * 4 + 2], m3 = ma[p * 4 + 3];
            #pragma unroll
            for (int rr = 0; rr < 2; ++rr) {
                f32x2 acc = m0 * w2[0 * 2 + rr];
                acc = pk_fma(m1, w2[1 * 2 + rr], acc);
                acc = pk_fma(m2, w2[2 * 2 + rr], acc);
                acc = pk_fma(m3, w2[3 * 2 + rr], acc);
                vv[p * 2 + rr] = acc;
            }
        }
    };

    // ---- pass 0: R uniform 1/32 -> Rw = ap/32; also build S1,S2 ----
    {
        f32x2 t12[8], s12[8], s22[8];
        #pragma unroll
        for (int dd = 0; dd < 8; ++dd) { t12[dd] = 0.f; s12[dd] = 0.f; s22[dd] = 0.f; }
        float rsum = 0.f;
        for (int j = 0; j < IPT; ++j) {
            const int i = iBase + j;
            float wa[16], ma[16];
            const float4* w4 = (const float4*)(Wg + ((size_t)((i << 5) + c) << 4));
            ((float4*)wa)[0] = w4[0]; ((float4*)wa)[1] = w4[1];
            ((float4*)wa)[2] = w4[2]; ((float4*)wa)[3] = w4[3];
            const float4* mp4 = (const float4*)(&MpL[H][i << 4]);
            ((float4*)ma)[0] = mp4[0]; ((float4*)ma)[1] = mp4[1];
            ((float4*)ma)[2] = mp4[2]; ((float4*)ma)[3] = mp4[3];
            float rw = apL[H][i] * 0.03125f;
            rsum += rw;
            f32x2 vv[8];
            computeV(wa, ma, vv);
            f32x2 rw2 = rw;
            #pragma unroll
            for (int dd = 0; dd < 8; ++dd) {
                t12[dd] = pk_fma(rw2, vv[dd], t12[dd]);
                s12[dd] += vv[dd];
                s22[dd] = pk_fma(vv[dd], vv[dd], s22[dd]);
            }
        }
        // unpack, combine partner half-waves (lane^32 shares c), then atomics
        float t1[16], s1[16], s2[16];
        #pragma unroll
        for (int dd = 0; dd < 8; ++dd) {
            t1[2 * dd] = t12[dd].x; t1[2 * dd + 1] = t12[dd].y;
            s1[2 * dd] = s12[dd].x; s1[2 * dd + 1] = s12[dd].y;
            s2[2 * dd] = s22[dd].x; s2[2 * dd + 1] = s22[dd].y;
        }
        rsum += __shfl_xor(rsum, 32);
        #pragma unroll
        for (int d = 0; d < 16; ++d) {
            t1[d] += __shfl_xor(t1[d], 32);
            s1[d] += __shfl_xor(s1[d], 32);
            s2[d] += __shfl_xor(s2[d], 32);
        }
        if ((u & 32) == 0) {
            atomicAdd(&RsumL[H][c], rsum);
            #pragma unroll
            for (int d = 0; d < 16; ++d) {
                atomicAdd(&T1L[H][c * ST + d], t1[d]);
                atomicAdd(&S1L[H][c * ST + d], s1[d]);
                atomicAdd(&S2L[H][c * ST + d], s2[d]);
            }
        }
        __syncthreads();
        statsA();
        __syncthreads();
        statsB(1.0f);   // it = 0
        __syncthreads();
    }

    // ---- passes 1,2: fused E-step (softmax over c, in-register) + M-step ----
    for (int it = 1; it < 3; ++it) {
        f32x2 Mr2[8], i2n[8];   // i2n = -(0.5/var)*log2e  (packed, pre-negated)
        #pragma unroll
        for (int dd = 0; dd < 8; ++dd) {
            Mr2[dd].x = ML[H][c * ST + 2 * dd];
            Mr2[dd].y = ML[H][c * ST + 2 * dd + 1];
            i2n[dd].x = -I2L[H][c * ST + 2 * dd];
            i2n[dd].y = -I2L[H][c * ST + 2 * dd + 1];
        }
        float Kc2 = (constL[H][c] - KmaxL[H]) * L2E;  // exp2 arg <= 0 always
        __syncthreads();                       // all reads done before re-zero
        for (int idx = u; idx < NC * ST; idx += UNIT) T1L[H][idx] = 0.f;
        if (u < NC) RsumL[H][u] = 0.f;
        __syncthreads();

        f32x2 t12[8];
        #pragma unroll
        for (int dd = 0; dd < 8; ++dd) t12[dd] = 0.f;
        float rsum = 0.f;
        for (int j = 0; j < IPT; ++j) {
            const int i = iBase + j;
            float wa[16], ma[16];
            const float4* w4 = (const float4*)(Wg + ((size_t)((i << 5) + c) << 4));
            ((float4*)wa)[0] = w4[0]; ((float4*)wa)[1] = w4[1];
            ((float4*)wa)[2] = w4[2]; ((float4*)wa)[3] = w4[3];
            const float4* mp4 = (const float4*)(&MpL[H][i << 4]);
            ((float4*)ma)[0] = mp4[0]; ((float4*)ma)[1] = mp4[1];
            ((float4*)ma)[2] = mp4[2]; ((float4*)ma)[3] = mp4[3];
            float a_i = apL[H][i];
            f32x2 vv[8];
            computeV(wa, ma, vv);
            // quadratic: two 4-deep packed chains; i2n pre-negated
            f32x2 qa = 0.f, qb = 0.f;
            #pragma unroll
            for (int dd = 0; dd < 4; ++dd) {
                f32x2 df = vv[dd] - Mr2[dd];
                qa = pk_fma(df, df * i2n[dd], qa);
            }
            #pragma unroll
            for (int dd = 4; dd < 8; ++dd) {
                f32x2 df = vv[dd] - Mr2[dd];
                qb = pk_fma(df, df * i2n[dd], qb);
            }
            f32x2 qs = qa + qb;
            float ex = exp2f(Kc2 + qs.x + qs.y); // <= 1; denom >= e^-8: safe
            // softmax denominator over the 32 caps of this half-wave:
            // DPP row sum (lane bits 0-3) + one cross-row shfl (bit 4)
            float ssum = row_sum16(ex);
            ssum += __shfl_xor(ssum, 16);
            float rw = ex * rcp_fast(ssum) * a_i;
            rsum += rw;
            f32x2 rw2 = rw;
            #pragma unroll
            for (int dd = 0; dd < 8; ++dd) t12[dd] = pk_fma(rw2, vv[dd], t12[dd]);
        }
        float t1[16];
        #pragma unroll
        for (int dd = 0; dd < 8; ++dd) {
            t1[2 * dd] = t12[dd].x; t1[2 * dd + 1] = t12[dd].y;
        }
        rsum += __shfl_xor(rsum, 32);
        #pragma unroll
        for (int d = 0; d < 16; ++d) t1[d] += __shfl_xor(t1[d], 32);
        if ((u & 32) == 0) {
            atomicAdd(&RsumL[H][c], rsum);
            #pragma unroll
            for (int d = 0; d < 16; ++d) atomicAdd(&T1L[H][c * ST + d], t1[d]);
        }
        __syncthreads();
        statsA();
        __syncthreads();
        statsB(1.0f + (float)it);   // inv_temp = 1 + it
        __syncthreads();
    }

    // ---- epilogue: out[pos,c,0:16]=M, out[pos,c,16]=sigmoid(a_j) ----
    // output stride per capsule is 17 == ST, so ML indexes line up directly.
    for (int idx = u; idx < NC * 17; idx += UNIT) {
        int cc = idx / 17;
        int e = idx - cc * 17;
        float val = (e < 16) ? ML[H][idx] : aoutL[H][cc];
        out[(size_t)pos * (NC * 17) + idx] = val;
    }
}

extern "C" void kernel_launch(void* const* d_in, const int* in_sizes, int n_in,
                              void* d_out, int out_size, void* d_ws, size_t ws_size,
                              hipStream_t stream) {
    const float* x  = (const float*)d_in[0];
    const float* W  = (const float*)d_in[1];
    const float* bv = (const float*)d_in[2];
    const float* ba = (const float*)d_in[3];
    float* out = (float*)d_out;
    // 288 positions, 2 per block => grid 144 <= 256 CUs: single dispatch round
    caps_em_kernel<<<144, NTHREADS, 0, stream>>>(x, W, bv, ba, out);
}